// Round 1
// baseline (593.258 us; speedup 1.0000x reference)
//
#include <hip/hip_runtime.h>
#include <stdint.h>

#define NV 163842
#define PARTS 512
#define EPSV 1e-5f

using short8 = __attribute__((ext_vector_type(8))) short;   // 8 bf16 (4 VGPRs)
using f32x4  = __attribute__((ext_vector_type(4))) float;   // MFMA acc

static __device__ __forceinline__ float bf2f(unsigned short u) {
    union { unsigned int i; float f; } v; v.i = ((unsigned int)u) << 16; return v.f;
}
static __device__ __forceinline__ unsigned short f2bf(float f) {
    union { float f; unsigned int i; } v; v.f = f;
    return (unsigned short)((v.i + 0x7FFFu + ((v.i >> 16) & 1u)) >> 16);  // RNE
}
// unpack packed pair of bf16 (low elem = low 16 bits)
static __device__ __forceinline__ void bf2x(unsigned int w, float& a, float& b) {
    union { unsigned int i; float f; } lo, hi;
    lo.i = w << 16; hi.i = w & 0xFFFF0000u;
    a = lo.f; b = hi.f;
}

// ---- cast input x (fp32 [N,64]) into concat buffer C (bf16, row stride 256) ----
__global__ __launch_bounds__(256) void k_cast(const float* __restrict__ x,
                                              unsigned short* __restrict__ C) {
    int e = blockIdx.x * 256 + threadIdx.x;          // unit = 4 floats
    if (e >= NV * 16) return;
    int v = e >> 4;
    int c = (e & 15) << 2;
    float4 f = *(const float4*)(x + (size_t)v * 64 + c);
    ushort4 u;
    u.x = f2bf(f.x); u.y = f2bf(f.y); u.z = f2bf(f.z); u.w = f2bf(f.w);
    *(ushort4*)(C + (size_t)v * 256 + c) = u;
}

// ---- per-channel sum / sumsq partial reduction over vertex dim ----
template<int CIN>
__global__ __launch_bounds__(256) void k_reduce(const unsigned short* __restrict__ C,
                                                float* __restrict__ part) {
    constexpr int TPR = CIN / 8;        // threads per row (8 channels each)
    constexpr int RPB = 256 / TPR;      // rows in flight per block
    constexpr int ACTIVE = TPR * RPB;
    int t = threadIdx.x, b = blockIdx.x;
    int c8 = t % TPR, ro = t / TPR;
    float s[8], s2[8];
#pragma unroll
    for (int j = 0; j < 8; ++j) { s[j] = 0.f; s2[j] = 0.f; }
    if (t < ACTIVE) {
        for (int row = b * RPB + ro; row < NV; row += PARTS * RPB) {
            uint4 u = *(const uint4*)(C + (size_t)row * 256 + c8 * 8);
            float f[8];
            bf2x(u.x, f[0], f[1]); bf2x(u.y, f[2], f[3]);
            bf2x(u.z, f[4], f[5]); bf2x(u.w, f[6], f[7]);
#pragma unroll
            for (int j = 0; j < 8; ++j) { s[j] += f[j]; s2[j] += f[j] * f[j]; }
        }
    }
    __shared__ float red[2048];
#pragma unroll
    for (int j = 0; j < 8; ++j) red[t * 8 + j] = s[j];
    __syncthreads();
    if (t < TPR) {
        float a[8];
#pragma unroll
        for (int j = 0; j < 8; ++j) a[j] = red[t * 8 + j];
        for (int r2 = 1; r2 < RPB; ++r2)
#pragma unroll
            for (int j = 0; j < 8; ++j) a[j] += red[(r2 * TPR + t) * 8 + j];
#pragma unroll
        for (int j = 0; j < 8; ++j) part[(size_t)b * 512 + t * 8 + j] = a[j];
    }
    __syncthreads();
#pragma unroll
    for (int j = 0; j < 8; ++j) red[t * 8 + j] = s2[j];
    __syncthreads();
    if (t < TPR) {
        float a[8];
#pragma unroll
        for (int j = 0; j < 8; ++j) a[j] = red[t * 8 + j];
        for (int r2 = 1; r2 < RPB; ++r2)
#pragma unroll
            for (int j = 0; j < 8; ++j) a[j] += red[(r2 * TPR + t) * 8 + j];
#pragma unroll
        for (int j = 0; j < 8; ++j) part[(size_t)b * 512 + 256 + t * 8 + j] = a[j];
    }
}

// ---- fold mean/var + g/b into scale/shift ----
__global__ __launch_bounds__(256) void k_finalize(const float* __restrict__ part,
                                                  const float* __restrict__ g,
                                                  const float* __restrict__ bb,
                                                  float* __restrict__ ss, int cin) {
    int t = threadIdx.x;
    if (t >= cin) return;
    float s = 0.f, s2 = 0.f;
    for (int p = 0; p < PARTS; ++p) {
        s  += part[(size_t)p * 512 + t];
        s2 += part[(size_t)p * 512 + 256 + t];
    }
    float mu  = s * (1.0f / NV);
    float var = s2 * (1.0f / NV) - mu * mu;   // biased var, matches jnp.var
    float sc  = g[t] * rsqrtf(var + EPSV);
    ss[t] = sc;
    ss[256 + t] = bb[t] - mu * sc;
}

// ---- y = lrelu(C*scale + shift) -> Y (bf16, row stride CIN) ----
template<int CIN>
__global__ __launch_bounds__(256) void k_apply(const unsigned short* __restrict__ C,
                                               const float* __restrict__ ss,
                                               unsigned short* __restrict__ Y) {
    __shared__ float ssc[256], ssh[256];
    int t = threadIdx.x;
    ssc[t] = ss[t]; ssh[t] = ss[256 + t];
    __syncthreads();
    int e = blockIdx.x * 256 + t;                 // unit = 8 channels
    constexpr int TOT8 = (int)((long long)NV * CIN / 8);
    if (e >= TOT8) return;
    int base = e * 8;
    int v = base / CIN;
    int c = base - v * CIN;
    uint4 u = *(const uint4*)(C + (size_t)v * 256 + c);
    float f[8];
    bf2x(u.x, f[0], f[1]); bf2x(u.y, f[2], f[3]);
    bf2x(u.z, f[4], f[5]); bf2x(u.w, f[6], f[7]);
    unsigned int ob[8];
#pragma unroll
    for (int j = 0; j < 8; ++j) {
        float yv = f[j] * ssc[c + j] + ssh[c + j];
        yv = yv > 0.f ? yv : 0.2f * yv;
        ob[j] = f2bf(yv);
    }
    uint4 o;
    o.x = ob[0] | (ob[1] << 16); o.y = ob[2] | (ob[3] << 16);
    o.z = ob[4] | (ob[5] << 16); o.w = ob[6] | (ob[7] << 16);
    *(uint4*)(Y + (size_t)v * CIN + c) = o;
}

// ---- W [7cin,64] fp32 -> Wt [64,7cin] bf16 (transposed so B-frags are contiguous) ----
__global__ __launch_bounds__(256) void k_wt(const float* __restrict__ W,
                                            unsigned short* __restrict__ Wt, int K7) {
    int j = blockIdx.x * 256 + threadIdx.x;
    if (j >= 64 * K7) return;
    int n = j / K7, k = j - n * K7;
    Wt[j] = f2bf(W[(size_t)k * 64 + n]);
}

// ---- gather + GEMM: out[v,0:64] = sum_r Y[neigh[7v+r],:] @ W[r*cin:(r+1)*cin,:] + wb ----
template<int CIN, bool FINAL>
__global__ __launch_bounds__(256) void k_gg(const unsigned short* __restrict__ Y,
                                            const int* __restrict__ neigh,
                                            const unsigned short* __restrict__ Wt,
                                            const float* __restrict__ wb,
                                            unsigned short* __restrict__ Cout,
                                            float* __restrict__ Fout) {
    constexpr int K7 = 7 * CIN;
    __shared__ int sIdx[448];
    __shared__ unsigned short sA[64 * 72];   // 64 rows x 64 bf16, +8 pad (b128 conflict-free)
    __shared__ unsigned short sW[64 * 72];
    const int t = threadIdx.x;
    const int v0 = blockIdx.x * 64;

    for (int q = t; q < 448; q += 256) {
        int gi = v0 * 7 + q;
        sIdx[q] = (gi < NV * 7) ? neigh[gi] : 0;
    }
    __syncthreads();

    const int wv = t >> 6, lane = t & 63;
    const int m = lane & 15, quad = lane >> 4;
    const int row = t >> 2, q4 = t & 3;     // staging: 4 threads per row, 16 bf16 each

    f32x4 acc[4];
#pragma unroll
    for (int i = 0; i < 4; ++i) acc[i] = f32x4{0.f, 0.f, 0.f, 0.f};

    const int aRd = (wv * 16 + m) * 72 + quad * 8;

    for (int r = 0; r < 7; ++r) {
        const int kidx = sIdx[row * 7 + r];
        const unsigned short* ybase = Y + (size_t)kidx * CIN;
#pragma unroll
        for (int kb = 0; kb < CIN; kb += 64) {
            const uint4* srcA = (const uint4*)(ybase + kb + q4 * 16);
            uint4 a0 = srcA[0], a1 = srcA[1];
            const uint4* srcW = (const uint4*)(Wt + (size_t)row * K7 + r * CIN + kb + q4 * 16);
            uint4 w0 = srcW[0], w1 = srcW[1];
            *(uint4*)(sA + row * 72 + q4 * 16)     = a0;
            *(uint4*)(sA + row * 72 + q4 * 16 + 8) = a1;
            *(uint4*)(sW + row * 72 + q4 * 16)     = w0;
            *(uint4*)(sW + row * 72 + q4 * 16 + 8) = w1;
            __syncthreads();
#pragma unroll
            for (int s = 0; s < 2; ++s) {
                short8 af = *(const short8*)(sA + aRd + s * 32);
#pragma unroll
                for (int ct = 0; ct < 4; ++ct) {
                    short8 bf = *(const short8*)(sW + (ct * 16 + m) * 72 + s * 32 + quad * 8);
                    acc[ct] = __builtin_amdgcn_mfma_f32_16x16x32_bf16(af, bf, acc[ct], 0, 0, 0);
                }
            }
            __syncthreads();
        }
    }
    // epilogue: D row = quad*4+reg, col = ct*16 + (lane&15)  [m89-verified layout]
#pragma unroll
    for (int ct = 0; ct < 4; ++ct) {
        int col = ct * 16 + m;
        float bv = wb[col];
#pragma unroll
        for (int j = 0; j < 4; ++j) {
            int vr = v0 + wv * 16 + quad * 4 + j;
            if (vr < NV) {
                float val = acc[ct][j] + bv;
                if (FINAL) Fout[(size_t)vr * 64 + col] = val;
                else       Cout[(size_t)vr * 256 + col] = f2bf(val);
            }
        }
    }
}

template<int CIN, bool FINAL>
static void run_layer(const unsigned short* C, unsigned short* Yb, unsigned short* WT,
                      float* PART, float* SS, const int* neigh,
                      const float* g, const float* bb, const float* W, const float* wb,
                      unsigned short* Cout, float* Fout, hipStream_t stream) {
    k_reduce<CIN><<<PARTS, 256, 0, stream>>>(C, PART);
    k_finalize<<<1, 256, 0, stream>>>(PART, g, bb, SS, CIN);
    constexpr int TOT8 = (int)((long long)NV * CIN / 8);
    k_apply<CIN><<<(TOT8 + 255) / 256, 256, 0, stream>>>(C, SS, Yb);
    const int K7 = 7 * CIN;
    k_wt<<<(64 * K7 + 255) / 256, 256, 0, stream>>>(W, WT, K7);
    k_gg<CIN, FINAL><<<(NV + 63) / 64, 256, 0, stream>>>(Yb, neigh, WT, wb, Cout, Fout);
}

extern "C" void kernel_launch(void* const* d_in, const int* in_sizes, int n_in,
                              void* d_out, int out_size, void* d_ws, size_t ws_size,
                              hipStream_t stream) {
    const float* x     = (const float*)d_in[0];
    const int*   neigh = (const int*)d_in[1];
    // dict order: g1,b1,W1,wb1, g2,b2,W2,wb2, g3,b3,W3,wb3, g4,b4,W4,wb4
    const float* G[4]  = {(const float*)d_in[2],  (const float*)d_in[6],
                          (const float*)d_in[10], (const float*)d_in[14]};
    const float* B[4]  = {(const float*)d_in[3],  (const float*)d_in[7],
                          (const float*)d_in[11], (const float*)d_in[15]};
    const float* W[4]  = {(const float*)d_in[4],  (const float*)d_in[8],
                          (const float*)d_in[12], (const float*)d_in[16]};
    const float* WB[4] = {(const float*)d_in[5],  (const float*)d_in[9],
                          (const float*)d_in[13], (const float*)d_in[17]};
    float* out = (float*)d_out;

    char* ws = (char*)d_ws;
    size_t off = 0;
    unsigned short* C  = (unsigned short*)(ws + off); off += (size_t)NV * 256 * 2;  // concat x|x1|x2|x3
    unsigned short* Yb = (unsigned short*)(ws + off); off += (size_t)NV * 256 * 2;  // BN+lrelu output
    unsigned short* WT = (unsigned short*)(ws + off); off += (size_t)64 * 1792 * 2; // transposed bf16 W
    float* PART        = (float*)(ws + off);          off += (size_t)PARTS * 512 * 4;
    float* SS          = (float*)(ws + off);          off += 512 * 4;

    k_cast<<<(NV * 16 + 255) / 256, 256, 0, stream>>>(x, C);
    run_layer< 64, false>(C, Yb, WT, PART, SS, neigh, G[0], B[0], W[0], WB[0], C +  64, nullptr, stream);
    run_layer<128, false>(C, Yb, WT, PART, SS, neigh, G[1], B[1], W[1], WB[1], C + 128, nullptr, stream);
    run_layer<192, false>(C, Yb, WT, PART, SS, neigh, G[2], B[2], W[2], WB[2], C + 192, nullptr, stream);
    run_layer<256, true >(C, Yb, WT, PART, SS, neigh, G[3], B[3], W[3], WB[3], nullptr, out,     stream);
}

// Round 2
// 528.003 us; speedup vs baseline: 1.1236x; 1.1236x over previous
//
#include <hip/hip_runtime.h>
#include <stdint.h>

#define NV 163842
#define EPSV 1e-5f

using short8 = __attribute__((ext_vector_type(8))) short;   // 8 bf16 (4 VGPRs)
using f32x4  = __attribute__((ext_vector_type(4))) float;   // MFMA acc

static __device__ __forceinline__ unsigned short f2bf(float f) {
    union { float f; unsigned int i; } v; v.f = f;
    return (unsigned short)((v.i + 0x7FFFu + ((v.i >> 16) & 1u)) >> 16);  // RNE
}
static __device__ __forceinline__ void bf2x(unsigned int w, float& a, float& b) {
    union { unsigned int i; float f; } lo, hi;
    lo.i = w << 16; hi.i = w & 0xFFFF0000u;
    a = lo.f; b = hi.f;
}
// pack two fp32 -> bf16x2 with round-half-up (+0x8000) and v_perm byte select
static __device__ __forceinline__ unsigned int pack2(float a, float b) {
    union { float f; unsigned int i; } ua, ub; ua.f = a; ub.f = b;
    return __builtin_amdgcn_perm(ub.i + 0x8000u, ua.i + 0x8000u, 0x07060302);
}

// ---- zero the stats accumulator (ws re-poisoned every call) ----
__global__ __launch_bounds__(256) void k_zero(float* __restrict__ ACC) {
    ACC[threadIdx.x] = 0.f;
    ACC[256 + threadIdx.x] = 0.f;
}

// ---- cast x fp32->bf16 into C cols [0,64); accumulate per-channel sum/sumsq ----
__global__ __launch_bounds__(256) void k_cast(const float* __restrict__ x,
                                              unsigned short* __restrict__ C,
                                              float* __restrict__ ACC) {
    const int t = threadIdx.x;
    const int wv = t >> 6, lane = t & 63;
    const int v = blockIdx.x * 64 + (t >> 2);
    const int c0 = (t & 3) * 16;
    float f[16];
    const bool valid = v < NV;
    if (valid) {
        const float4* p = (const float4*)(x + (size_t)v * 64 + c0);
#pragma unroll
        for (int i = 0; i < 4; ++i) {
            float4 q = p[i];
            f[i * 4 + 0] = q.x; f[i * 4 + 1] = q.y; f[i * 4 + 2] = q.z; f[i * 4 + 3] = q.w;
        }
        unsigned int o[8];
#pragma unroll
        for (int i = 0; i < 8; ++i)
            o[i] = ((unsigned int)f2bf(f[2 * i])) | (((unsigned int)f2bf(f[2 * i + 1])) << 16);
        uint4* dst = (uint4*)(C + (size_t)v * 256 + c0);
        dst[0] = uint4{o[0], o[1], o[2], o[3]};
        dst[1] = uint4{o[4], o[5], o[6], o[7]};
    } else {
#pragma unroll
        for (int i = 0; i < 16; ++i) f[i] = 0.f;
    }
    float s[16], s2[16];
#pragma unroll
    for (int i = 0; i < 16; ++i) { s[i] = f[i]; s2[i] = f[i] * f[i]; }
#pragma unroll
    for (int mask = 4; mask <= 32; mask <<= 1) {
#pragma unroll
        for (int i = 0; i < 16; ++i) {
            s[i]  += __shfl_xor(s[i],  mask);
            s2[i] += __shfl_xor(s2[i], mask);
        }
    }
    __shared__ float red[4 * 128];
    if ((lane >> 2) == 0) {
        int cb = (lane & 3) * 16;
#pragma unroll
        for (int i = 0; i < 16; ++i) {
            red[wv * 128 + cb + i]      = s[i];
            red[wv * 128 + 64 + cb + i] = s2[i];
        }
    }
    __syncthreads();
    if (t < 128) {
        float v4 = red[t] + red[128 + t] + red[256 + t] + red[384 + t];
        int c = t & 63, which = t >> 6;
        atomicAdd(&ACC[which * 256 + c], v4);
    }
}

// ---- transpose all four W [7cin,64] fp32 -> WT [64,7cin] bf16, one launch ----
__global__ __launch_bounds__(256) void k_wt_all(const float* __restrict__ W1,
                                                const float* __restrict__ W2,
                                                const float* __restrict__ W3,
                                                const float* __restrict__ W4,
                                                unsigned short* __restrict__ WT) {
    int j = blockIdx.x * 256 + threadIdx.x;
    if (j >= 286720) return;
    const float* W; int jj, K7;
    if (j < 28672)       { W = W1; jj = j;          K7 = 448;  }
    else if (j < 86016)  { W = W2; jj = j - 28672;  K7 = 896;  }
    else if (j < 172032) { W = W3; jj = j - 86016;  K7 = 1344; }
    else                 { W = W4; jj = j - 172032; K7 = 1792; }
    int n = jj / K7, k = jj - n * K7;
    WT[j] = f2bf(W[(size_t)k * 64 + n]);
}

// ---- fused: BN(scale/shift from ACC)+lrelu on gathered rows -> MFMA -> out + stats ----
template<int CIN, int GRP, bool FINAL>
__global__ __launch_bounds__(256) void k_gg(const unsigned short* __restrict__ C,
                                            const int* __restrict__ neigh,
                                            const unsigned short* __restrict__ WT,
                                            const float* __restrict__ g,
                                            const float* __restrict__ bglob,
                                            const float* __restrict__ wb,
                                            float* __restrict__ ACC,
                                            unsigned short* __restrict__ Cout,
                                            float* __restrict__ Fout) {
    constexpr int KB = CIN / 64;      // K-chunks per neighbor
    constexpr int NC = 7 * KB;        // total 64-wide K chunks
    constexpr int K7 = 7 * CIN;       // WT row stride

    __shared__ float ssc[256], ssh[256];
    __shared__ int sIdx[896];
    __shared__ unsigned short sA[128 * 72];
    __shared__ unsigned short sW[64 * 72];

    const int t = threadIdx.x;
    const int v0 = blockIdx.x * 128;

    if (t < CIN) {  // fold stats+g+b into scale/shift (recomputed per block, ~free)
        float s = ACC[t], s2 = ACC[256 + t];
        float mu = s * (1.0f / NV);
        float var = fmaf(-mu, mu, s2 * (1.0f / NV));
        float sc = g[t] * rsqrtf(var + EPSV);
        ssc[t] = sc;
        ssh[t] = bglob[t] - mu * sc;
    }
    for (int q = t; q < 896; q += 256) {
        int gi = v0 * 7 + q;
        sIdx[q] = (gi < NV * 7) ? neigh[gi] : 0;
    }
    __syncthreads();

    const int wv = t >> 6, lane = t & 63;
    const int m = lane & 15, quad = lane >> 4;
    const int arow = t >> 1, ahalf = t & 1;   // A staging: 2 thr/row, 64 B each
    const int wrow = t >> 2, wq = t & 3;      // W staging: 4 thr/row, 32 B each

    f32x4 acc[2][4];
#pragma unroll
    for (int i = 0; i < 2; ++i)
#pragma unroll
        for (int j = 0; j < 4; ++j) acc[i][j] = f32x4{0.f, 0.f, 0.f, 0.f};

    auto load_chunk = [&](int c, uint4* aa, uint4& x0, uint4& x1) {
        int r = c / KB, kb = c - r * KB;
        int src = sIdx[arow * 7 + r];
        const uint4* pa = (const uint4*)(C + (size_t)src * 256 + kb * 64 + ahalf * 32);
        aa[0] = pa[0]; aa[1] = pa[1]; aa[2] = pa[2]; aa[3] = pa[3];
        const uint4* pw = (const uint4*)(WT + (size_t)wrow * K7 + c * 64 + wq * 16);
        x0 = pw[0]; x1 = pw[1];
    };
    auto stage = [&](const uint4* aa, uint4 x0, uint4 x1, int c) {
        int kb = c - (c / KB) * KB;
        int chb = kb * 64 + ahalf * 32;
        unsigned short* dstA = sA + arow * 72 + ahalf * 32;
#pragma unroll
        for (int i = 0; i < 4; ++i) {
            unsigned int u[4] = {aa[i].x, aa[i].y, aa[i].z, aa[i].w};
            unsigned int o[4];
#pragma unroll
            for (int jj = 0; jj < 4; ++jj) {
                float lo, hi; bf2x(u[jj], lo, hi);
                int ch = chb + i * 8 + jj * 2;
                float y0 = fmaf(lo, ssc[ch],     ssh[ch]);
                float y1 = fmaf(hi, ssc[ch + 1], ssh[ch + 1]);
                y0 = y0 > 0.f ? y0 : 0.2f * y0;
                y1 = y1 > 0.f ? y1 : 0.2f * y1;
                o[jj] = pack2(y0, y1);
            }
            *(uint4*)(dstA + i * 8) = uint4{o[0], o[1], o[2], o[3]};
        }
        *(uint4*)(sW + wrow * 72 + wq * 16)     = x0;
        *(uint4*)(sW + wrow * 72 + wq * 16 + 8) = x1;
    };

    uint4 a[4], w0, w1;
    load_chunk(0, a, w0, w1);
#pragma unroll 2
    for (int c = 0; c < NC; ++c) {
        uint4 na[4], nw0, nw1;
        if (c + 1 < NC) load_chunk(c + 1, na, nw0, nw1);   // in flight across barriers+MFMA
        stage(a, w0, w1, c);
        __syncthreads();
#pragma unroll
        for (int s = 0; s < 2; ++s) {
            short8 af0 = *(const short8*)(sA + (wv * 32 + m) * 72      + s * 32 + quad * 8);
            short8 af1 = *(const short8*)(sA + (wv * 32 + 16 + m) * 72 + s * 32 + quad * 8);
#pragma unroll
            for (int ct = 0; ct < 4; ++ct) {
                short8 bf = *(const short8*)(sW + (ct * 16 + m) * 72 + s * 32 + quad * 8);
                acc[0][ct] = __builtin_amdgcn_mfma_f32_16x16x32_bf16(af0, bf, acc[0][ct], 0, 0, 0);
                acc[1][ct] = __builtin_amdgcn_mfma_f32_16x16x32_bf16(af1, bf, acc[1][ct], 0, 0, 0);
            }
        }
        __syncthreads();
        if (c + 1 < NC) {
#pragma unroll
            for (int i = 0; i < 4; ++i) a[i] = na[i];
            w0 = nw0; w1 = nw1;
        }
    }

    // epilogue: bias, write, per-channel stats for the produced 64-col group
    float bsum[4]  = {0.f, 0.f, 0.f, 0.f};
    float b2sum[4] = {0.f, 0.f, 0.f, 0.f};
#pragma unroll
    for (int mt = 0; mt < 2; ++mt) {
#pragma unroll
        for (int ct = 0; ct < 4; ++ct) {
            int col = ct * 16 + m;
            float bv = wb[col];
#pragma unroll
            for (int j = 0; j < 4; ++j) {
                int vr = v0 + wv * 32 + mt * 16 + quad * 4 + j;
                float val = acc[mt][ct][j] + bv;
                if (vr < NV) {
                    if (FINAL) {
                        Fout[(size_t)vr * 64 + col] = val;
                    } else {
                        Cout[(size_t)vr * 256 + GRP * 64 + col] = f2bf(val);
                        bsum[ct] += val; b2sum[ct] += val * val;
                    }
                }
            }
        }
    }
    if (!FINAL) {
#pragma unroll
        for (int ct = 0; ct < 4; ++ct) {   // reduce over quads (rows within wave)
            bsum[ct]  += __shfl_xor(bsum[ct], 16);
            bsum[ct]  += __shfl_xor(bsum[ct], 32);
            b2sum[ct] += __shfl_xor(b2sum[ct], 16);
            b2sum[ct] += __shfl_xor(b2sum[ct], 32);
        }
        float* red = (float*)sA;   // sA dead after last barrier
        if (quad == 0) {
#pragma unroll
            for (int ct = 0; ct < 4; ++ct) {
                red[wv * 128 + ct * 16 + m]       = bsum[ct];
                red[512 + wv * 128 + ct * 16 + m] = b2sum[ct];
            }
        }
        __syncthreads();
        if (t < 128) {
            int c = t & 63, which = t >> 6;
            float v = red[which * 512 + c] + red[which * 512 + 128 + c] +
                      red[which * 512 + 256 + c] + red[which * 512 + 384 + c];
            atomicAdd(&ACC[which * 256 + GRP * 64 + c], v);
        }
    }
}

extern "C" void kernel_launch(void* const* d_in, const int* in_sizes, int n_in,
                              void* d_out, int out_size, void* d_ws, size_t ws_size,
                              hipStream_t stream) {
    const float* x     = (const float*)d_in[0];
    const int*   neigh = (const int*)d_in[1];
    const float* G[4]  = {(const float*)d_in[2],  (const float*)d_in[6],
                          (const float*)d_in[10], (const float*)d_in[14]};
    const float* B[4]  = {(const float*)d_in[3],  (const float*)d_in[7],
                          (const float*)d_in[11], (const float*)d_in[15]};
    const float* W[4]  = {(const float*)d_in[4],  (const float*)d_in[8],
                          (const float*)d_in[12], (const float*)d_in[16]};
    const float* WB[4] = {(const float*)d_in[5],  (const float*)d_in[9],
                          (const float*)d_in[13], (const float*)d_in[17]};
    float* out = (float*)d_out;

    char* ws = (char*)d_ws;
    size_t off = 0;
    unsigned short* C  = (unsigned short*)(ws + off); off += (size_t)NV * 256 * 2;  // concat x|x1|x2|x3
    unsigned short* WT = (unsigned short*)(ws + off); off += (size_t)286720 * 2;    // all 4 transposed W
    float* ACC         = (float*)(ws + off);          off += 512 * 4;               // sum[256], sumsq[256]

    k_zero<<<1, 256, 0, stream>>>(ACC);
    k_cast<<<(NV + 63) / 64, 256, 0, stream>>>(x, C, ACC);
    k_wt_all<<<(286720 + 255) / 256, 256, 0, stream>>>(W[0], W[1], W[2], W[3], WT);

    const int GG = (NV + 127) / 128;
    k_gg< 64, 1, false><<<GG, 256, 0, stream>>>(C, neigh, WT,          G[0], B[0], WB[0], ACC, C, nullptr);
    k_gg<128, 2, false><<<GG, 256, 0, stream>>>(C, neigh, WT + 28672,  G[1], B[1], WB[1], ACC, C, nullptr);
    k_gg<192, 3, false><<<GG, 256, 0, stream>>>(C, neigh, WT + 86016,  G[2], B[2], WB[2], ACC, C, nullptr);
    k_gg<256, 0, true ><<<GG, 256, 0, stream>>>(C, neigh, WT + 172032, G[3], B[3], WB[3], ACC, nullptr, out);
}